// Round 1
// baseline (2925.739 us; speedup 1.0000x reference)
//
#include <hip/hip_runtime.h>

#define NN 20000      // nodes
#define NE 160000     // edges per edge set
#define NL 20         // EGNN layer calls (4*DEPTH)

typedef float f32x4 __attribute__((ext_vector_type(4)));
typedef __bf16 bf16x8 __attribute__((ext_vector_type(8)));

__device__ __forceinline__ float silu_f(float v) {
  return v / (1.f + __expf(-v));
}

// ---------------------------------------------------------------------------
// Pack fp32 weight matrix [L][K][128] into MFMA-B-fragment order:
// out[((layer*ktn + kt)*8 + nt)*64 + lane][8], elem j = W[kt*32+(lane>>4)*8+j][nt*16+(lane&15)]
// (A fragments use the same (group,j)->k map, so contraction is consistent.)
// ---------------------------------------------------------------------------
__global__ void pack_weights(const float* __restrict__ W, __bf16* __restrict__ out,
                             const int K, const int lstride, const int total) {
  const int idx = blockIdx.x * 256 + threadIdx.x;
  if (idx >= total) return;
  const int lane = idx & 63;
  const int nt = (idx >> 6) & 7;
  const int ktn = K >> 5;
  const int kt = (idx >> 9) % ktn;
  const int layer = (idx >> 9) / ktn;
  const int col = nt * 16 + (lane & 15);
  const int kb = kt * 32 + (lane >> 4) * 8;
  const float* src = W + (size_t)layer * lstride;
  __bf16* o = out + (size_t)idx * 8;
#pragma unroll
  for (int j = 0; j < 8; ++j) o[j] = (__bf16)src[(kb + j) * 128 + col];
}

// ---------------------------------------------------------------------------
__global__ void embed_kernel(const float* __restrict__ x, const float* __restrict__ embW,
                             const float* __restrict__ embB,
                             float* __restrict__ h, __bf16* __restrict__ hbf) {
  const int idx = blockIdx.x * 256 + threadIdx.x;   // grid sized exactly NN*128/256
  const int n = idx >> 7, d = idx & 127;
  const float v = x[n] * embW[d] + embB[d];
  h[idx] = v;
  hbf[idx] = (__bf16)v;
}

// ---------------------------------------------------------------------------
// Fused edge-message kernel: 64 edges/block, 4 waves.
//   m = concat(h[dst], h[src], dist) @ Wm1 + bm1 -> LN -> SiLU -> @Wm2 + bm2 -> LN -> SiLU
//   atomicAdd into agg[dst]
// ---------------------------------------------------------------------------
__global__ __launch_bounds__(256) void edge_kernel(
    const __bf16* __restrict__ hbf, const float* __restrict__ pos,
    const int* __restrict__ ei, float* __restrict__ agg,
    const __bf16* __restrict__ w1p, const __bf16* __restrict__ w2p,
    const float* __restrict__ w1last,
    const float* __restrict__ bm1, const float* __restrict__ gm1, const float* __restrict__ sm1,
    const float* __restrict__ bm2, const float* __restrict__ gm2, const float* __restrict__ sm2) {
  __shared__ __bf16 Asm[64 * 256];   // 32 KB, XOR-swizzled, K = [h_dst(128), h_src(128)]
  __shared__ __bf16 T1[64 * 128];    // 16 KB, XOR-swizzled intermediate
  __shared__ float distS[64];
  __shared__ int dstS[64];
  __shared__ float red[4][64][2];    // cross-wave LN partials (sum, sumsq)

  const int t = threadIdx.x;
  {
    const int e = t >> 2, p = t & 3;
    const int eg = blockIdx.x * 64 + e;
    const int vsrc = ei[eg];
    const int vdst = ei[NE + eg];
    const int idx = (p < 2) ? vdst : vsrc;
    const uint4* hrow = (const uint4*)(hbf + (size_t)idx * 128 + (p & 1) * 64);
    const int kb2 = (((p & 2) << 6) + ((p & 1) << 6)) << 1;  // byte offset of K-base within row
#pragma unroll
    for (int j = 0; j < 8; ++j) {
      uint4 v = hrow[j];
      const int byte = (e * 512 + kb2 + j * 16) ^ ((e & 7) << 4);
      *(uint4*)((char*)Asm + byte) = v;
    }
    if (p == 0) {
      const float dx = pos[vdst * 3 + 0] - pos[vsrc * 3 + 0];
      const float dy = pos[vdst * 3 + 1] - pos[vsrc * 3 + 1];
      const float dz = pos[vdst * 3 + 2] - pos[vsrc * 3 + 2];
      distS[e] = sqrtf(dx * dx + dy * dy + dz * dz);
      dstS[e] = vdst;
    }
  }
  __syncthreads();

  const int w = t >> 6, l = t & 63, lr = l & 15, lg = l >> 4;
  float g1c[2], s1c[2];
  f32x4 acc[4][2];
  // accumulator init = dist*Wm1[256] + bm1  (folds the 257th K-row + bias)
#pragma unroll
  for (int nt2 = 0; nt2 < 2; ++nt2) {
    const int col = (w * 2 + nt2) * 16 + lr;
    const float wl = w1last[col], bb = bm1[col];
    g1c[nt2] = gm1[col]; s1c[nt2] = sm1[col];
#pragma unroll
    for (int mt = 0; mt < 4; ++mt)
#pragma unroll
      for (int r = 0; r < 4; ++r)
        acc[mt][nt2][r] = distS[mt * 16 + lg * 4 + r] * wl + bb;
  }
  // GEMM1: [64 x 256] @ [256 x 128]
#pragma unroll
  for (int kt = 0; kt < 8; ++kt) {
    bf16x8 a[4];
#pragma unroll
    for (int mt = 0; mt < 4; ++mt) {
      const int row = mt * 16 + lr;
      const int byte = (row * 512 + kt * 64 + lg * 16) ^ ((row & 7) << 4);
      a[mt] = *(const bf16x8*)((const char*)Asm + byte);
    }
#pragma unroll
    for (int nt2 = 0; nt2 < 2; ++nt2) {
      const bf16x8 b = *(const bf16x8*)(w1p + ((size_t)((kt * 8 + w * 2 + nt2) * 64 + l)) * 8);
#pragma unroll
      for (int mt = 0; mt < 4; ++mt)
        acc[mt][nt2] = __builtin_amdgcn_mfma_f32_16x16x32_bf16(a[mt], b, acc[mt][nt2], 0, 0, 0);
    }
  }
  // LN1 cross-wave stats
#pragma unroll
  for (int mt = 0; mt < 4; ++mt)
#pragma unroll
    for (int r = 0; r < 4; ++r) {
      float s = acc[mt][0][r] + acc[mt][1][r];
      float q = acc[mt][0][r] * acc[mt][0][r] + acc[mt][1][r] * acc[mt][1][r];
#pragma unroll
      for (int m = 1; m < 16; m <<= 1) { s += __shfl_xor(s, m); q += __shfl_xor(q, m); }
      if (lr == 0) { const int row = mt * 16 + lg * 4 + r; red[w][row][0] = s; red[w][row][1] = q; }
    }
  __syncthreads();
#pragma unroll
  for (int mt = 0; mt < 4; ++mt)
#pragma unroll
    for (int r = 0; r < 4; ++r) {
      const int row = mt * 16 + lg * 4 + r;
      const float s = red[0][row][0] + red[1][row][0] + red[2][row][0] + red[3][row][0];
      const float q = red[0][row][1] + red[1][row][1] + red[2][row][1] + red[3][row][1];
      const float mu = s * 0.0078125f;
      const float rstd = rsqrtf(q * 0.0078125f - mu * mu + 1e-5f);
#pragma unroll
      for (int nt2 = 0; nt2 < 2; ++nt2) {
        float v = (acc[mt][nt2][r] - mu) * rstd * g1c[nt2] + s1c[nt2];
        v = silu_f(v);
        const int col = (w * 2 + nt2) * 16 + lr;
        const int byte = (row * 256 + col * 2) ^ ((row & 7) << 4);
        *(__bf16*)((char*)T1 + byte) = (__bf16)v;
      }
    }
  __syncthreads();
  // GEMM2: [64 x 128] @ [128 x 128]
  float g2c[2], s2c[2];
  f32x4 acc2[4][2];
#pragma unroll
  for (int nt2 = 0; nt2 < 2; ++nt2) {
    const int col = (w * 2 + nt2) * 16 + lr;
    const float bb = bm2[col];
    g2c[nt2] = gm2[col]; s2c[nt2] = sm2[col];
#pragma unroll
    for (int mt = 0; mt < 4; ++mt)
#pragma unroll
      for (int r = 0; r < 4; ++r) acc2[mt][nt2][r] = bb;
  }
#pragma unroll
  for (int kt = 0; kt < 4; ++kt) {
    bf16x8 a[4];
#pragma unroll
    for (int mt = 0; mt < 4; ++mt) {
      const int row = mt * 16 + lr;
      const int byte = (row * 256 + kt * 64 + lg * 16) ^ ((row & 7) << 4);
      a[mt] = *(const bf16x8*)((const char*)T1 + byte);
    }
#pragma unroll
    for (int nt2 = 0; nt2 < 2; ++nt2) {
      const bf16x8 b = *(const bf16x8*)(w2p + ((size_t)((kt * 8 + w * 2 + nt2) * 64 + l)) * 8);
#pragma unroll
      for (int mt = 0; mt < 4; ++mt)
        acc2[mt][nt2] = __builtin_amdgcn_mfma_f32_16x16x32_bf16(a[mt], b, acc2[mt][nt2], 0, 0, 0);
    }
  }
  // LN2 + SiLU + atomic scatter into agg[dst]
#pragma unroll
  for (int mt = 0; mt < 4; ++mt)
#pragma unroll
    for (int r = 0; r < 4; ++r) {
      float s = acc2[mt][0][r] + acc2[mt][1][r];
      float q = acc2[mt][0][r] * acc2[mt][0][r] + acc2[mt][1][r] * acc2[mt][1][r];
#pragma unroll
      for (int m = 1; m < 16; m <<= 1) { s += __shfl_xor(s, m); q += __shfl_xor(q, m); }
      if (lr == 0) { const int row = mt * 16 + lg * 4 + r; red[w][row][0] = s; red[w][row][1] = q; }
    }
  __syncthreads();
#pragma unroll
  for (int mt = 0; mt < 4; ++mt)
#pragma unroll
    for (int r = 0; r < 4; ++r) {
      const int row = mt * 16 + lg * 4 + r;
      const float s = red[0][row][0] + red[1][row][0] + red[2][row][0] + red[3][row][0];
      const float q = red[0][row][1] + red[1][row][1] + red[2][row][1] + red[3][row][1];
      const float mu = s * 0.0078125f;
      const float rstd = rsqrtf(q * 0.0078125f - mu * mu + 1e-5f);
      const int dn = dstS[row];
#pragma unroll
      for (int nt2 = 0; nt2 < 2; ++nt2) {
        float v = (acc2[mt][nt2][r] - mu) * rstd * g2c[nt2] + s2c[nt2];
        v = silu_f(v);
        const int col = (w * 2 + nt2) * 16 + lr;
        atomicAdd(&agg[(size_t)dn * 128 + col], v);
      }
    }
}

// ---------------------------------------------------------------------------
// Fused node-update kernel: u = concat(h, agg) -> 2-layer MLP; in-place h update
// (+ residual h0 when addRes), maintains bf16 mirror.
// ---------------------------------------------------------------------------
__global__ __launch_bounds__(256) void update_kernel(
    float* __restrict__ h, const float* __restrict__ aggv, __bf16* __restrict__ hbf,
    const float* __restrict__ h0, const int addRes,
    const __bf16* __restrict__ w1p, const __bf16* __restrict__ w2p,
    const float* __restrict__ bu1, const float* __restrict__ gu1, const float* __restrict__ su1,
    const float* __restrict__ bu2, const float* __restrict__ gu2, const float* __restrict__ su2) {
  __shared__ __bf16 Asm[64 * 256];
  __shared__ __bf16 T1[64 * 128];
  __shared__ float red[4][64][2];

  const int t = threadIdx.x;
  const int n0 = blockIdx.x * 64;
  {
    const int e = t >> 2, p = t & 3;
    const int n = n0 + e;
    const float vm = (n < NN) ? 1.f : 0.f;
    const int nn = (n < NN) ? n : 0;
    const f32x4* s4 = (const f32x4*)(((p < 2) ? h : aggv) + (size_t)nn * 128 + (p & 1) * 64);
    const int kb2 = (((p & 2) << 6) + ((p & 1) << 6)) << 1;
#pragma unroll
    for (int j = 0; j < 8; ++j) {
      const f32x4 v0 = s4[2 * j], v1 = s4[2 * j + 1];
      bf16x8 cv;
#pragma unroll
      for (int q = 0; q < 4; ++q) { cv[q] = (__bf16)(v0[q] * vm); cv[q + 4] = (__bf16)(v1[q] * vm); }
      const int byte = (e * 512 + kb2 + j * 16) ^ ((e & 7) << 4);
      *(bf16x8*)((char*)Asm + byte) = cv;
    }
  }
  __syncthreads();

  const int w = t >> 6, l = t & 63, lr = l & 15, lg = l >> 4;
  float g1c[2], s1c[2];
  f32x4 acc[4][2];
#pragma unroll
  for (int nt2 = 0; nt2 < 2; ++nt2) {
    const int col = (w * 2 + nt2) * 16 + lr;
    const float bb = bu1[col];
    g1c[nt2] = gu1[col]; s1c[nt2] = su1[col];
#pragma unroll
    for (int mt = 0; mt < 4; ++mt)
#pragma unroll
      for (int r = 0; r < 4; ++r) acc[mt][nt2][r] = bb;
  }
#pragma unroll
  for (int kt = 0; kt < 8; ++kt) {
    bf16x8 a[4];
#pragma unroll
    for (int mt = 0; mt < 4; ++mt) {
      const int row = mt * 16 + lr;
      const int byte = (row * 512 + kt * 64 + lg * 16) ^ ((row & 7) << 4);
      a[mt] = *(const bf16x8*)((const char*)Asm + byte);
    }
#pragma unroll
    for (int nt2 = 0; nt2 < 2; ++nt2) {
      const bf16x8 b = *(const bf16x8*)(w1p + ((size_t)((kt * 8 + w * 2 + nt2) * 64 + l)) * 8);
#pragma unroll
      for (int mt = 0; mt < 4; ++mt)
        acc[mt][nt2] = __builtin_amdgcn_mfma_f32_16x16x32_bf16(a[mt], b, acc[mt][nt2], 0, 0, 0);
    }
  }
#pragma unroll
  for (int mt = 0; mt < 4; ++mt)
#pragma unroll
    for (int r = 0; r < 4; ++r) {
      float s = acc[mt][0][r] + acc[mt][1][r];
      float q = acc[mt][0][r] * acc[mt][0][r] + acc[mt][1][r] * acc[mt][1][r];
#pragma unroll
      for (int m = 1; m < 16; m <<= 1) { s += __shfl_xor(s, m); q += __shfl_xor(q, m); }
      if (lr == 0) { const int row = mt * 16 + lg * 4 + r; red[w][row][0] = s; red[w][row][1] = q; }
    }
  __syncthreads();
#pragma unroll
  for (int mt = 0; mt < 4; ++mt)
#pragma unroll
    for (int r = 0; r < 4; ++r) {
      const int row = mt * 16 + lg * 4 + r;
      const float s = red[0][row][0] + red[1][row][0] + red[2][row][0] + red[3][row][0];
      const float q = red[0][row][1] + red[1][row][1] + red[2][row][1] + red[3][row][1];
      const float mu = s * 0.0078125f;
      const float rstd = rsqrtf(q * 0.0078125f - mu * mu + 1e-5f);
#pragma unroll
      for (int nt2 = 0; nt2 < 2; ++nt2) {
        float v = (acc[mt][nt2][r] - mu) * rstd * g1c[nt2] + s1c[nt2];
        v = silu_f(v);
        const int col = (w * 2 + nt2) * 16 + lr;
        const int byte = (row * 256 + col * 2) ^ ((row & 7) << 4);
        *(__bf16*)((char*)T1 + byte) = (__bf16)v;
      }
    }
  __syncthreads();
  float g2c[2], s2c[2];
  f32x4 acc2[4][2];
#pragma unroll
  for (int nt2 = 0; nt2 < 2; ++nt2) {
    const int col = (w * 2 + nt2) * 16 + lr;
    const float bb = bu2[col];
    g2c[nt2] = gu2[col]; s2c[nt2] = su2[col];
#pragma unroll
    for (int mt = 0; mt < 4; ++mt)
#pragma unroll
      for (int r = 0; r < 4; ++r) acc2[mt][nt2][r] = bb;
  }
#pragma unroll
  for (int kt = 0; kt < 4; ++kt) {
    bf16x8 a[4];
#pragma unroll
    for (int mt = 0; mt < 4; ++mt) {
      const int row = mt * 16 + lr;
      const int byte = (row * 256 + kt * 64 + lg * 16) ^ ((row & 7) << 4);
      a[mt] = *(const bf16x8*)((const char*)T1 + byte);
    }
#pragma unroll
    for (int nt2 = 0; nt2 < 2; ++nt2) {
      const bf16x8 b = *(const bf16x8*)(w2p + ((size_t)((kt * 8 + w * 2 + nt2) * 64 + l)) * 8);
#pragma unroll
      for (int mt = 0; mt < 4; ++mt)
        acc2[mt][nt2] = __builtin_amdgcn_mfma_f32_16x16x32_bf16(a[mt], b, acc2[mt][nt2], 0, 0, 0);
    }
  }
#pragma unroll
  for (int mt = 0; mt < 4; ++mt)
#pragma unroll
    for (int r = 0; r < 4; ++r) {
      float s = acc2[mt][0][r] + acc2[mt][1][r];
      float q = acc2[mt][0][r] * acc2[mt][0][r] + acc2[mt][1][r] * acc2[mt][1][r];
#pragma unroll
      for (int m = 1; m < 16; m <<= 1) { s += __shfl_xor(s, m); q += __shfl_xor(q, m); }
      if (lr == 0) { const int row = mt * 16 + lg * 4 + r; red[w][row][0] = s; red[w][row][1] = q; }
    }
  __syncthreads();
#pragma unroll
  for (int mt = 0; mt < 4; ++mt)
#pragma unroll
    for (int r = 0; r < 4; ++r) {
      const int row = mt * 16 + lg * 4 + r;
      const float s = red[0][row][0] + red[1][row][0] + red[2][row][0] + red[3][row][0];
      const float q = red[0][row][1] + red[1][row][1] + red[2][row][1] + red[3][row][1];
      const float mu = s * 0.0078125f;
      const float rstd = rsqrtf(q * 0.0078125f - mu * mu + 1e-5f);
      const int n = n0 + row;
      if (n < NN) {
#pragma unroll
        for (int nt2 = 0; nt2 < 2; ++nt2) {
          const int col = (w * 2 + nt2) * 16 + lr;
          float v = (acc2[mt][nt2][r] - mu) * rstd * g2c[nt2] + s2c[nt2];
          v = silu_f(v);
          if (addRes) v += h0[(size_t)n * 128 + col];
          h[(size_t)n * 128 + col] = v;
          hbf[(size_t)n * 128 + col] = (__bf16)v;
        }
      }
    }
}

// ---------------------------------------------------------------------------
__global__ void pool_kernel(const float* __restrict__ h, const int* __restrict__ bid,
                            float* __restrict__ pooled) {
  const int idx = blockIdx.x * 256 + threadIdx.x;   // grid sized exactly NN*128/256
  const int n = idx >> 7;
  atomicAdd(&pooled[bid[n] * 128 + (idx & 127)], h[idx]);
}

__global__ void head_kernel(const float* __restrict__ pooled,
                            const float* __restrict__ W1, const float* __restrict__ b1,
                            const float* __restrict__ W2, const float* __restrict__ b2,
                            float* __restrict__ out) {
  __shared__ float buf[2];
  const int b = blockIdx.x, t = threadIdx.x;
  float s = b1[t];
  for (int k = 0; k < 128; ++k) s += pooled[b * 128 + k] * W1[k * 128 + t];
  s = fmaxf(s, 0.f) * W2[t];
#pragma unroll
  for (int m = 32; m >= 1; m >>= 1) s += __shfl_down(s, m);
  if ((t & 63) == 0) buf[t >> 6] = s;
  __syncthreads();
  if (t == 0) out[b] = buf[0] + buf[1] + b2[0];
}

// ---------------------------------------------------------------------------
extern "C" void kernel_launch(void* const* d_in, const int* in_sizes, int n_in,
                              void* d_out, int out_size, void* d_ws, size_t ws_size,
                              hipStream_t stream) {
  const float* x   = (const float*)d_in[0];
  const float* pos = (const float*)d_in[1];
  const int* eis[4] = {(const int*)d_in[2], (const int*)d_in[3],
                       (const int*)d_in[4], (const int*)d_in[5]};
  const int* bid = (const int*)d_in[6];
  const float* embW = (const float*)d_in[7];
  const float* embB = (const float*)d_in[8];
  const float* Wm1 = (const float*)d_in[9];
  const float* bm1 = (const float*)d_in[10];
  const float* gm1 = (const float*)d_in[11];
  const float* sm1 = (const float*)d_in[12];
  const float* Wm2 = (const float*)d_in[13];
  const float* bm2 = (const float*)d_in[14];
  const float* gm2 = (const float*)d_in[15];
  const float* sm2 = (const float*)d_in[16];
  const float* Wu1 = (const float*)d_in[17];
  const float* bu1 = (const float*)d_in[18];
  const float* gu1 = (const float*)d_in[19];
  const float* su1 = (const float*)d_in[20];
  const float* Wu2 = (const float*)d_in[21];
  const float* bu2 = (const float*)d_in[22];
  const float* gu2 = (const float*)d_in[23];
  const float* su2 = (const float*)d_in[24];
  const float* pW1 = (const float*)d_in[25];
  const float* pb1 = (const float*)d_in[26];
  const float* pW2 = (const float*)d_in[27];
  const float* pb2 = (const float*)d_in[28];
  float* out = (float*)d_out;

  char* wp = (char*)d_ws;
  float* h = (float*)wp;      wp += (size_t)NN * 128 * 4;
  float* h0 = (float*)wp;     wp += (size_t)NN * 128 * 4;
  float* agg = (float*)wp;    wp += (size_t)NN * 128 * 4;
  float* pooled = (float*)wp; wp += 16 * 128 * 4;
  __bf16* hbf = (__bf16*)wp;  wp += (size_t)NN * 128 * 2;
  __bf16* w1p = (__bf16*)wp;  wp += (size_t)NL * 32768 * 2;  // Wm1 (K=256 part), packed
  __bf16* w2p = (__bf16*)wp;  wp += (size_t)NL * 16384 * 2;  // Wm2
  __bf16* wu1p = (__bf16*)wp; wp += (size_t)NL * 32768 * 2;  // Wu1
  __bf16* wu2p = (__bf16*)wp; wp += (size_t)NL * 16384 * 2;  // Wu2

  // Pack weights (recomputed every call; ~2M elems, trivial)
  pack_weights<<<320, 256, 0, stream>>>(Wm1, w1p, 256, 257 * 128, NL * 8 * 8 * 64);
  pack_weights<<<160, 256, 0, stream>>>(Wm2, w2p, 128, 128 * 128, NL * 4 * 8 * 64);
  pack_weights<<<320, 256, 0, stream>>>(Wu1, wu1p, 256, 256 * 128, NL * 8 * 8 * 64);
  pack_weights<<<160, 256, 0, stream>>>(Wu2, wu2p, 128, 128 * 128, NL * 4 * 8 * 64);

  embed_kernel<<<(NN * 128) / 256, 256, 0, stream>>>(x, embW, embB, h, hbf);

  for (int layer = 0; layer < 5; ++layer) {
    hipMemcpyAsync(h0, h, (size_t)NN * 128 * 4, hipMemcpyDeviceToDevice, stream);
    for (int r = 0; r < 4; ++r) {
      const int i = layer * 4 + r;
      hipMemsetAsync(agg, 0, (size_t)NN * 128 * 4, stream);
      edge_kernel<<<NE / 64, 256, 0, stream>>>(
          hbf, pos, eis[r], agg,
          w1p + (size_t)i * 32768, w2p + (size_t)i * 16384,
          Wm1 + (size_t)i * 257 * 128 + 256 * 128,
          bm1 + i * 128, gm1 + i * 128, sm1 + i * 128,
          bm2 + i * 128, gm2 + i * 128, sm2 + i * 128);
      update_kernel<<<(NN + 63) / 64, 256, 0, stream>>>(
          h, agg, hbf, h0, (r == 3) ? 1 : 0,
          wu1p + (size_t)i * 32768, wu2p + (size_t)i * 16384,
          bu1 + i * 128, gu1 + i * 128, su1 + i * 128,
          bu2 + i * 128, gu2 + i * 128, su2 + i * 128);
    }
  }

  hipMemsetAsync(pooled, 0, 16 * 128 * 4, stream);
  pool_kernel<<<(NN * 128) / 256, 256, 0, stream>>>(h, bid, pooled);
  head_kernel<<<16, 128, 0, stream>>>(pooled, pW1, pb1, pW2, pb2, out);
}